// Round 14
// baseline (52.277 us; speedup 1.0000x reference)
//
#include <hip/hip_runtime.h>
#include <hip/hip_bf16.h>
#include <math.h>

#define NVOX 262144   // 64^3

// ---- helpers ----
__device__ __forceinline__ unsigned short f2bf(float x) {
    __hip_bfloat16 h = __float2bfloat16(x);
    return *reinterpret_cast<unsigned short*>(&h);
}
__device__ __forceinline__ float bf2f(unsigned short u) {
    __hip_bfloat16 h = *reinterpret_cast<__hip_bfloat16*>(&u);
    return __bfloat162float(h);
}
// squared distance (u16, 0xFFFF acts as +inf) from lane w to nearest set bit
__device__ __forceinline__ unsigned short dist2_u16(unsigned long long mask, int w) {
    if (mask == 0ull) return 0xFFFFu;
    unsigned long long mr = mask >> w;          // bits k >= w
    unsigned long long ml = mask << (63 - w);   // bits k <= w
    int dr = mr ? __builtin_ctzll(mr) : 127;
    int dl = ml ? __builtin_clzll(ml) : 127;
    int dd = dr < dl ? dr : dl;
    return (unsigned short)(dd * dd);
}

// =====================================================================
// D1: fused. Blocks [0,768): EDT pass-1 (W, ballot) + pass-2 (H,
// early-exit) from targets -> bufA (u16). Blocks [768,1792): pure-stream
// warm of preds (4 float4/thread, coalesced, full occupancy) -> sink.
// The EDT compute overlaps the unavoidable cold preds read window.
// =====================================================================
__global__ __launch_bounds__(256) void D1_warm_edt(
    const float* __restrict__ preds, const int* __restrict__ targets,
    unsigned short* __restrict__ bufA, float* __restrict__ sink) {
    __shared__ unsigned short tO[64 * 66];
    __shared__ unsigned short tI[64 * 66];
    int bid = blockIdx.x;
    int t = threadIdx.x, lane = t & 63, wid = t >> 6;

    if (bid >= 768) {
        // ---------- warm path: stream all of preds ----------
        int tid = (bid - 768) * 256 + t;               // [0, 262144)
        const float4* p4 = (const float4*)preds;       // 1,048,576 float4s
        float4 a = p4[tid];
        float4 b = p4[tid + 262144];
        float4 c = p4[tid + 2 * 262144];
        float4 d = p4[tid + 3 * 262144];
        float acc = a.x + a.y + a.z + a.w + b.x + b.y + b.z + b.w
                  + c.x + c.y + c.z + c.w + d.x + d.y + d.z + d.w;
        #pragma unroll
        for (int o = 32; o > 0; o >>= 1) acc += __shfl_down(acc, o);
        if (lane == 0) sink[(bid - 768) * 4 + wid] = acc;
        return;
    }

    // ---------- EDT path ----------
    int cm = bid % 3;
    int bd = bid / 3;            // b*64 + d
    int d = bd & 63, b = bd >> 6;
    int c = cm + 1;
    const int* tg = targets + (size_t)b * NVOX + (size_t)d * 4096;

    #pragma unroll
    for (int i = 0; i < 16; ++i) {
        int e = t + 256 * i;
        int h = wid + 4 * i;
        int tv = tg[e];
        unsigned long long mask = __ballot(tv == c);
        tO[h * 66 + lane] = dist2_u16(mask, lane);
        tI[h * 66 + lane] = dist2_u16(~mask, lane);
    }
    __syncthreads();

    // pass-2 along H: wave owns 16 cols w = wid*16+r; lane = h. Early-exit.
    for (int r = 0; r < 16; ++r) {
        int w = wid * 16 + r;
        {
            unsigned best = tO[lane * 66 + w];
            for (int dk = 1; dk < 64; ++dk) {
                unsigned d2 = (unsigned)(dk * dk);
                if (__all(d2 >= best)) break;
                int hl = lane - dk; hl = hl < 0 ? 0 : hl;
                int hr = lane + dk; hr = hr > 63 ? 63 : hr;
                unsigned ca = tO[hl * 66 + w] + d2;
                unsigned cb = tO[hr * 66 + w] + d2;
                ca = ca < cb ? ca : cb;
                best = best < ca ? best : ca;
            }
            tO[lane * 66 + w] = (unsigned short)best;   // lockstep: safe in-place
        }
        {
            unsigned best = tI[lane * 66 + w];
            for (int dk = 1; dk < 64; ++dk) {
                unsigned d2 = (unsigned)(dk * dk);
                if (__all(d2 >= best)) break;
                int hl = lane - dk; hl = hl < 0 ? 0 : hl;
                int hr = lane + dk; hr = hr > 63 ? 63 : hr;
                unsigned ca = tI[hl * 66 + w] + d2;
                unsigned cb = tI[hr * 66 + w] + d2;
                ca = ca < cb ? ca : cb;
                best = best < ca ? best : ca;
            }
            tI[lane * 66 + w] = (unsigned short)best;
        }
    }
    __syncthreads();

    int combo = b * 3 + cm;
    size_t oO = (size_t)combo * NVOX + (size_t)d * 64;
    size_t oI = (size_t)(combo + 12) * NVOX + (size_t)d * 64;
    #pragma unroll
    for (int i = 0; i < 16; ++i) {
        int h = wid + 4 * i;
        bufA[oO + (size_t)h * 4096 + lane] = tO[h * 66 + lane];
        bufA[oI + (size_t)h * 4096 + lane] = tI[h * 66 + lane];
    }
}

// =====================================================================
// D2: stats + bf16 probsT on (now warm) preds. 1024 blocks x 256 thr,
// 4 voxels/thread. probsT[combo][h][d][w] bf16.
// =====================================================================
__global__ __launch_bounds__(256) void D2_stats_probs(
    const float* __restrict__ preds, const int* __restrict__ targets,
    unsigned short* __restrict__ probsT, float* __restrict__ part_stats) {
    __shared__ float sred[4 * 13];
    int bid = blockIdx.x, t = threadIdx.x, lane = t & 63, wid = t >> 6;
    int g0 = bid * 1024 + 4 * t;
    int b = g0 >> 18;
    int v0 = g0 & (NVOX - 1);
    const float* p = preds + (size_t)(b * 4) * NVOX + v0;
    float4 x0 = *(const float4*)(p);
    float4 x1 = *(const float4*)(p + NVOX);
    float4 x2 = *(const float4*)(p + 2 * NVOX);
    float4 x3 = *(const float4*)(p + 3 * NVOX);
    int4 tv4 = *(const int4*)(targets + (size_t)b * NVOX + v0);

    const float L2E = 1.4426950408889634f;
    const float LN2 = 0.6931471805599453f;
    float q[13];
    #pragma unroll
    for (int k = 0; k < 13; ++k) q[k] = 0.0f;
    unsigned short pb[3][4];

    #pragma unroll
    for (int j = 0; j < 4; ++j) {
        float a0 = (&x0.x)[j], a1 = (&x1.x)[j], a2 = (&x2.x)[j], a3 = (&x3.x)[j];
        int tv = (&tv4.x)[j];
        float m  = fmaxf(fmaxf(a0, a1), fmaxf(a2, a3));
        float e0 = exp2f((a0 - m) * L2E);
        float e1 = exp2f((a1 - m) * L2E);
        float e2 = exp2f((a2 - m) * L2E);
        float e3 = exp2f((a3 - m) * L2E);
        float ssum = e0 + e1 + e2 + e3;
        float inv  = __builtin_amdgcn_rcpf(ssum);
        float p0 = e0 * inv, p1 = e1 * inv, p2 = e2 * inv, p3 = e3 * inv;
        float xt = (tv == 0) ? a0 : (tv == 1) ? a1 : (tv == 2) ? a2 : a3;
        q[12] += (m - xt) + log2f(ssum) * LN2;
        q[4] += p0; q[5] += p1; q[6] += p2; q[7] += p3;
        if (tv == 0)      { q[0] += p0; q[8]  += 1.0f; }
        else if (tv == 1) { q[1] += p1; q[9]  += 1.0f; }
        else if (tv == 2) { q[2] += p2; q[10] += 1.0f; }
        else              { q[3] += p3; q[11] += 1.0f; }
        pb[0][j] = f2bf(p1); pb[1][j] = f2bf(p2); pb[2][j] = f2bf(p3);
    }

    int d = v0 >> 12, h = (v0 >> 6) & 63, w0 = v0 & 63;
    size_t poff = (size_t)h * 4096 + d * 64 + w0;
    #pragma unroll
    for (int c = 0; c < 3; ++c) {
        ushort4 u = make_ushort4(pb[c][0], pb[c][1], pb[c][2], pb[c][3]);
        *(ushort4*)(probsT + (size_t)(b * 3 + c) * NVOX + poff) = u;
    }

    #pragma unroll
    for (int k = 0; k < 13; ++k) {
        float x = q[k];
        #pragma unroll
        for (int o = 32; o > 0; o >>= 1) x += __shfl_down(x, o);
        if (lane == 0) sred[wid * 13 + k] = x;
    }
    __syncthreads();
    if (t < 13) {
        float s = sred[t] + sred[13 + t] + sred[26 + t] + sred[39 + t];
        part_stats[t * 1024 + bid] = s;
    }
}

// =====================================================================
// D3: EDT pass-3 (D, early-exit) + sdf*prob reduce -> one float per block.
// grid = 768 (combo*64 + h), 512 thr.
// =====================================================================
__global__ __launch_bounds__(512) void D3_edt3_sdf(
    const unsigned short* __restrict__ bufA, const unsigned short* __restrict__ probsT,
    float* __restrict__ part_bound) {
    __shared__ float pl[2][64 * 65];
    __shared__ float sredb[8];
    int blk = blockIdx.x;
    int combo = blk >> 6, h = blk & 63;
    int t = threadIdx.x, lane = t & 63, wid = t >> 6;

    for (int v = 0; v < 2; ++v) {
        const unsigned short* src = bufA + (size_t)(combo + 12 * v) * NVOX + (size_t)h * 4096;
        #pragma unroll
        for (int i = 0; i < 8; ++i) {
            int e = t + 512 * i;                     // e = d*64 + w
            pl[v][e + (e >> 6)] = (float)src[e];     // lds[d*65+w]
        }
    }
    __syncthreads();

    // pass along D: wave owns cols w = wid*8+r; lane = d. Early-exit.
    for (int v = 0; v < 2; ++v) {
        for (int r = 0; r < 8; ++r) {
            int w = wid * 8 + r;
            float* col = &pl[v][w];
            float best = col[lane * 65];
            for (int dk = 1; dk < 64; ++dk) {
                float d2 = (float)(dk * dk);
                if (__all(d2 >= best)) break;
                int dl = lane - dk; dl = dl < 0 ? 0 : dl;
                int dr = lane + dk; dr = dr > 63 ? 63 : dr;
                best = fminf(fminf(best, col[dl * 65] + d2), col[dr * 65] + d2);
            }
            col[lane * 65] = best;
        }
    }
    __syncthreads();

    const unsigned short* pp = probsT + (size_t)combo * NVOX + (size_t)h * 4096;
    float acc = 0.0f;
    #pragma unroll
    for (int i = 0; i < 8; ++i) {
        int e = t + 512 * i;
        int li = e + (e >> 6);
        float sdf = sqrtf(pl[0][li]) - sqrtf(pl[1][li]);
        acc += sdf * bf2f(pp[e]);
    }
    #pragma unroll
    for (int o = 32; o > 0; o >>= 1) acc += __shfl_down(acc, o);
    if (lane == 0) sredb[wid] = acc;
    __syncthreads();
    if (t == 0) {
        float s = 0.0f;
        for (int j = 0; j < 8; ++j) s += sredb[j];
        part_bound[blk] = s;
    }
}

// =====================================================================
// D4: single block; loads up-front, shfl/LDS reduce, f64 combine + guards.
// part_stats rows 1024 wide (256 blocks per batch; b = entry>>8).
// =====================================================================
__global__ __launch_bounds__(1024) void D4_final(
    const float* __restrict__ part_stats, const float* __restrict__ part_bound,
    float* __restrict__ out) {
    __shared__ float sred[13 * 16];
    __shared__ float bred[12];
    __shared__ double S[52];
    int t = threadIdx.x, lane = t & 63, wid = t >> 6;

    float v[13];
    #pragma unroll
    for (int k = 0; k < 13; ++k) v[k] = part_stats[k * 1024 + t];
    float bv = (wid < 12) ? part_bound[wid * 64 + lane] : 0.0f;

    #pragma unroll
    for (int k = 0; k < 13; ++k) {
        float x = v[k];
        #pragma unroll
        for (int o = 32; o > 0; o >>= 1) x += __shfl_down(x, o);
        if (lane == 0) sred[k * 16 + wid] = x;
    }
    #pragma unroll
    for (int o = 32; o > 0; o >>= 1) bv += __shfl_down(bv, o);
    if (lane == 0 && wid < 12) bred[wid] = bv;
    __syncthreads();

    if (t < 52) {   // k = t>>2, b = t&3; 4 waves per b
        int k = t >> 2, b = t & 3;
        S[k * 4 + b] = (double)sred[k * 16 + b * 4]     + (double)sred[k * 16 + b * 4 + 1]
                     + (double)sred[k * 16 + b * 4 + 2] + (double)sred[k * 16 + b * 4 + 3];
    }
    __syncthreads();
    if (t == 0) {
        const double NV = (double)NVOX;
        double dice_sum = 0.0;
        for (int b = 0; b < 4; ++b)
            for (int c = 0; c < 4; ++c) {
                double inter = S[c * 4 + b];
                double un    = S[(4 + c) * 4 + b] + S[(8 + c) * 4 + b];
                dice_sum += (2.0 * inter + 1e-5) / (un + 1e-5);
            }
        double l_dice = 1.0 - dice_sum / 16.0;
        double l_ce = (S[48] + S[49] + S[50] + S[51]) / (4.0 * NV);
        double lb = 0.0;
        for (int cb = 0; cb < 12; ++cb) {
            int b = cb / 3, c = cb % 3 + 1;
            double cnt = S[(8 + c) * 4 + b];
            double s;
            if (cnt == 0.0)      s =  S[(4 + c) * 4 + b];   // sdf == +1 everywhere
            else if (cnt == NV)  s = -S[(4 + c) * 4 + b];   // sdf == -1 everywhere
            else                 s =  (double)bred[cb];
            lb += s / NV;
        }
        lb /= 12.0;
        out[0] = (float)(l_dice + l_ce + 0.01 * lb);
    }
}

extern "C" void kernel_launch(void* const* d_in, const int* in_sizes, int n_in,
                              void* d_out, int out_size, void* d_ws, size_t ws_size,
                              hipStream_t stream) {
    const float* preds   = (const float*)d_in[0];
    const int*   targets = (const int*)d_in[1];
    float* out = (float*)d_out;

    // workspace: bufA u16 (12.6 MB) | probsT bf16 (6.3 MB) | partials | sink
    unsigned short* bufA   = (unsigned short*)d_ws;
    unsigned short* probsT = bufA + (size_t)24 * NVOX;
    float* part_stats = (float*)(probsT + (size_t)12 * NVOX);
    float* part_bound = part_stats + 13 * 1024;
    float* sink       = part_bound + 768;

    D1_warm_edt<<<1792, 256, 0, stream>>>(preds, targets, bufA, sink);
    D2_stats_probs<<<1024, 256, 0, stream>>>(preds, targets, probsT, part_stats);
    D3_edt3_sdf<<<768, 512, 0, stream>>>(bufA, probsT, part_bound);
    D4_final<<<1, 1024, 0, stream>>>(part_stats, part_bound, out);
}